// Round 13
// baseline (985.473 us; speedup 1.0000x reference)
//
#include <hip/hip_runtime.h>
#include <math.h>

// ---------------------------------------------------------------------------
// VQ-VAE 3D forward, round 20.
// r19 post-mortem: 998->984; convt2 TZ=2 out of top-5. Top = conv2 @193.5us:
// swizzle fixed traffic (FETCH 222->40MB, HBM 3.9%) but VALU back at 33%,
// occupancy 35% -> latency-bound, double-capped (grid 1024 = 4 blk/CU AND
// waves_per_eu(2,4) = 16 waves/CU). Stall math: covering ~200cy L2 latency
// per weight-chain needs ~8 waves/SIMD, have 2.8. Every ILP fix failed
// (r9-r17); the untried lever is TLP.
// r20, ONE mechanism, conv2 only: OCG 16->8, NG 2->4 (grid 2048 = 8 blk/CU,
// VGPR ~40) + k_conv_hi clone with waves_per_eu(2,8). conv1/conv3 stay on
// the (2,4) original byte-identical (r14 proved (2,8) poisons fetch-heavy
// conv1). Everything else = r19.
// ---------------------------------------------------------------------------

__device__ __forceinline__ float4 ld4(const float* p) {
  float4 q; __builtin_memcpy(&q, p, 16); return q;
}
struct F3 { float x, y, z; };
__device__ __forceinline__ F3 ld3(const float* p) {
  F3 q; __builtin_memcpy(&q, p, 12); return q;
}

#define WAVES_HINT __attribute__((amdgpu_waves_per_eu(2, 4)))
#define WAVES_HINT_HI __attribute__((amdgpu_waves_per_eu(2, 8)))

// ---------------- convT weight repack: -> Wp[ci][p][co][2][8] ---------------
// src w[ci][co][kz*16+ky*4+kx] (PyTorch convT layout).
// For parity p=(pz,py,px) and octet-tap a=(az,ay,ax): k = 3-p-2a per axis.
// Slot: group g=az holds j=ay*2+ax in [0,4); slots 4..7 of each group unused.
template<int CIN, int COUT>
__global__ __launch_bounds__(256) void k_repackT(const float* __restrict__ w,
                                                 float* __restrict__ dst) {
  const int idx = blockIdx.x * 256 + threadIdx.x;
  if (idx >= CIN * 8 * COUT * 8) return;
  const int a  = idx & 7;
  const int co = (idx >> 3) % COUT;
  const int p  = ((idx >> 3) / COUT) & 7;
  const int ci2 = idx / (8 * COUT * 8);
  const int az = a >> 2, ay = (a >> 1) & 1, ax = a & 1;
  const int pz = p >> 2, py = (p >> 1) & 1, px = p & 1;
  const int kz = 3 - pz - 2 * az, ky = 3 - py - 2 * ay, kx = 3 - px - 2 * ax;
  dst[(((size_t)(ci2 * 8 + p) * COUT + co) * 16) + az * 8 + (ay * 2 + ax)] =
      w[((size_t)ci2 * COUT + co) * 64 + (kz * 16 + ky * 4 + kx)];
}

// ---------------- halo zeroing for padded buffers ---------------------------
template<int S, int D, int NCH>
__global__ __launch_bounds__(256) void k_zhalo(float* __restrict__ buf) {
  const int vol = S * S * S;
  const long long idx = (long long)blockIdx.x * 256 + threadIdx.x;
  if (idx >= (long long)NCH * vol) return;
  const int r = (int)(idx % vol);
  const int z = r / (S * S), y = (r / S) % S, x = r % S;
  if (z < 1 || z > D || y < 1 || y > D || x < 1 || x > D) buf[idx] = 0.0f;
}

// ---------------- pad raw input x [4][128^3] -> dp [4][130^3] ---------------
__global__ __launch_bounds__(256) void k_pad(const float* __restrict__ x,
                                             float* __restrict__ dp) {
  constexpr long long VOL = 130LL * 130 * 130;
  const long long idx = (long long)blockIdx.x * 256 + threadIdx.x;
  if (idx >= 4 * VOL) return;
  const int b = (int)(idx / VOL);
  const int r = (int)(idx % VOL);
  const int z = r / (130 * 130), y = (r / 130) % 130, xx = r % 130;
  float v = 0.0f;
  if (z >= 1 && z <= 128 && y >= 1 && y <= 128 && xx >= 1 && xx <= 128)
    v = x[(((long long)b * 128 + (z - 1)) * 128 + (y - 1)) * 128 + (xx - 1)];
  dp[idx] = v;
}

// ---------------- forward conv (k=4,s=2,p=1) --------------------------------
// r3/r13-proven body (global weights, one x4 tuple per consume point).
// r18: XCD-aware block swizzle (NWG%8==0 guaranteed by launch configs).
template<int CIN, int COUT, int DIN, int DOUT, int OCG, int TZ, bool RELU,
         bool INP, int SIN, bool OUTP, int SOUT, int NG>
__global__ __launch_bounds__(256) WAVES_HINT
void k_conv(const float* __restrict__ xin, const float* __restrict__ wg,
            const float* __restrict__ bias, float* __restrict__ out) {
  constexpr int NBX = DOUT / 8, NBY = DOUT / 8, NBZ = DOUT / (4 * TZ);
  constexpr int NWG = 4 * NG * NBX * NBY * NBZ;
  static_assert(NWG % 8 == 0, "bijective XCD swizzle needs NWG%8==0");
  constexpr size_t VIN  = INP  ? (size_t)SIN * SIN * SIN : (size_t)DIN * DIN * DIN;
  constexpr size_t VOUT = OUTP ? (size_t)SOUT * SOUT * SOUT : (size_t)DOUT * DOUT * DOUT;
  const int tid = threadIdx.x;
  const int tx = tid & 7, ty = (tid >> 3) & 7, tz = tid >> 6;
  const int bid = blockIdx.x;
  int bb = (bid & 7) * (NWG / 8) + (bid >> 3);
  const int g  = bb % NG;  bb /= NG;
  const int gx = bb % NBX; bb /= NBX;
  const int gy = bb % NBY; bb /= NBY;
  const int gz = bb % NBZ; bb /= NBZ;
  const int b = bb;
  const int oc0 = g * OCG;
  const int ow = gx * 8 + tx, oh = gy * 8 + ty, od0 = gz * (4 * TZ) + tz;

  float acc[TZ][OCG];
#pragma unroll
  for (int j = 0; j < TZ; ++j)
#pragma unroll
    for (int c = 0; c < OCG; ++c) acc[j][c] = 0.0f;

#pragma unroll 1
  for (int ci = 0; ci < CIN; ++ci) {
    const float* xb = xin + (size_t)(b * CIN + ci) * VIN;
#pragma unroll 1
    for (int t16 = 0; t16 < 16; ++t16) {   // t16 = kd*4 + kh
      float4 q[TZ];
      if (INP) {
        const int zp = od0 * 2 + (t16 >> 2);
        const int yp = oh * 2 + (t16 & 3);
        const float* r0 = xb + ((size_t)zp * SIN + yp) * SIN + ow * 2;
#pragma unroll
        for (int j = 0; j < TZ; ++j) q[j] = ld4(r0 + (size_t)j * 8 * SIN * SIN);
      } else {
        const int y  = oh * 2 - 1 + (t16 & 3);
        const int x0 = ow * 2 - 1;
        const bool vy = (unsigned)y < (unsigned)DIN;
#pragma unroll
        for (int j = 0; j < TZ; ++j) {
          const int z = od0 * 2 - 1 + (t16 >> 2) + j * 8;
          const bool vz = vy && ((unsigned)z < (unsigned)DIN);
          const float* xr = xb + ((size_t)z * DIN + y) * DIN + x0;
          q[j].x = (vz && (unsigned)(x0 + 0) < (unsigned)DIN) ? xr[0] : 0.0f;
          q[j].y = (vz && (unsigned)(x0 + 1) < (unsigned)DIN) ? xr[1] : 0.0f;
          q[j].z = (vz && (unsigned)(x0 + 2) < (unsigned)DIN) ? xr[2] : 0.0f;
          q[j].w = (vz && (unsigned)(x0 + 3) < (unsigned)DIN) ? xr[3] : 0.0f;
        }
      }
#pragma unroll
      for (int c = 0; c < OCG; ++c) {
        const float4 w4 = ld4(wg + ((size_t)(oc0 + c) * CIN + ci) * 64 + t16 * 4);
#pragma unroll
        for (int j = 0; j < TZ; ++j) {
          acc[j][c] = fmaf(q[j].x, w4.x, acc[j][c]);
          acc[j][c] = fmaf(q[j].y, w4.y, acc[j][c]);
          acc[j][c] = fmaf(q[j].z, w4.z, acc[j][c]);
          acc[j][c] = fmaf(q[j].w, w4.w, acc[j][c]);
        }
      }
    }
  }

#pragma unroll
  for (int c = 0; c < OCG; ++c) {
    const float bv = bias[oc0 + c];
#pragma unroll
    for (int j = 0; j < TZ; ++j) {
      float v = acc[j][c] + bv;
      if (RELU) v = fmaxf(v, 0.0f);
      const int od = od0 + j * 4;
      if (OUTP)
        out[(size_t)(b * COUT + oc0 + c) * VOUT
            + ((size_t)(od + 1) * SOUT + (oh + 1)) * SOUT + (ow + 1)] = v;
      else
        out[(size_t)(b * COUT + oc0 + c) * VOUT
            + ((size_t)od * DOUT + oh) * DOUT + ow] = v;
    }
  }
}

// ---------------- forward conv, high-residency clone ------------------------
// Byte-identical body to k_conv; only the waves hint differs (2,8). Used for
// L2-resident mid convs where latency hiding needs 8 waves/EU (r20: conv2).
template<int CIN, int COUT, int DIN, int DOUT, int OCG, int TZ, bool RELU,
         bool INP, int SIN, bool OUTP, int SOUT, int NG>
__global__ __launch_bounds__(256) WAVES_HINT_HI
void k_conv_hi(const float* __restrict__ xin, const float* __restrict__ wg,
               const float* __restrict__ bias, float* __restrict__ out) {
  constexpr int NBX = DOUT / 8, NBY = DOUT / 8, NBZ = DOUT / (4 * TZ);
  constexpr int NWG = 4 * NG * NBX * NBY * NBZ;
  static_assert(NWG % 8 == 0, "bijective XCD swizzle needs NWG%8==0");
  constexpr size_t VIN  = INP  ? (size_t)SIN * SIN * SIN : (size_t)DIN * DIN * DIN;
  constexpr size_t VOUT = OUTP ? (size_t)SOUT * SOUT * SOUT : (size_t)DOUT * DOUT * DOUT;
  const int tid = threadIdx.x;
  const int tx = tid & 7, ty = (tid >> 3) & 7, tz = tid >> 6;
  const int bid = blockIdx.x;
  int bb = (bid & 7) * (NWG / 8) + (bid >> 3);
  const int g  = bb % NG;  bb /= NG;
  const int gx = bb % NBX; bb /= NBX;
  const int gy = bb % NBY; bb /= NBY;
  const int gz = bb % NBZ; bb /= NBZ;
  const int b = bb;
  const int oc0 = g * OCG;
  const int ow = gx * 8 + tx, oh = gy * 8 + ty, od0 = gz * (4 * TZ) + tz;

  float acc[TZ][OCG];
#pragma unroll
  for (int j = 0; j < TZ; ++j)
#pragma unroll
    for (int c = 0; c < OCG; ++c) acc[j][c] = 0.0f;

#pragma unroll 1
  for (int ci = 0; ci < CIN; ++ci) {
    const float* xb = xin + (size_t)(b * CIN + ci) * VIN;
#pragma unroll 1
    for (int t16 = 0; t16 < 16; ++t16) {   // t16 = kd*4 + kh
      float4 q[TZ];
      if (INP) {
        const int zp = od0 * 2 + (t16 >> 2);
        const int yp = oh * 2 + (t16 & 3);
        const float* r0 = xb + ((size_t)zp * SIN + yp) * SIN + ow * 2;
#pragma unroll
        for (int j = 0; j < TZ; ++j) q[j] = ld4(r0 + (size_t)j * 8 * SIN * SIN);
      } else {
        const int y  = oh * 2 - 1 + (t16 & 3);
        const int x0 = ow * 2 - 1;
        const bool vy = (unsigned)y < (unsigned)DIN;
#pragma unroll
        for (int j = 0; j < TZ; ++j) {
          const int z = od0 * 2 - 1 + (t16 >> 2) + j * 8;
          const bool vz = vy && ((unsigned)z < (unsigned)DIN);
          const float* xr = xb + ((size_t)z * DIN + y) * DIN + x0;
          q[j].x = (vz && (unsigned)(x0 + 0) < (unsigned)DIN) ? xr[0] : 0.0f;
          q[j].y = (vz && (unsigned)(x0 + 1) < (unsigned)DIN) ? xr[1] : 0.0f;
          q[j].z = (vz && (unsigned)(x0 + 2) < (unsigned)DIN) ? xr[2] : 0.0f;
          q[j].w = (vz && (unsigned)(x0 + 3) < (unsigned)DIN) ? xr[3] : 0.0f;
        }
      }
#pragma unroll
      for (int c = 0; c < OCG; ++c) {
        const float4 w4 = ld4(wg + ((size_t)(oc0 + c) * CIN + ci) * 64 + t16 * 4);
#pragma unroll
        for (int j = 0; j < TZ; ++j) {
          acc[j][c] = fmaf(q[j].x, w4.x, acc[j][c]);
          acc[j][c] = fmaf(q[j].y, w4.y, acc[j][c]);
          acc[j][c] = fmaf(q[j].z, w4.z, acc[j][c]);
          acc[j][c] = fmaf(q[j].w, w4.w, acc[j][c]);
        }
      }
    }
  }

#pragma unroll
  for (int c = 0; c < OCG; ++c) {
    const float bv = bias[oc0 + c];
#pragma unroll
    for (int j = 0; j < TZ; ++j) {
      float v = acc[j][c] + bv;
      if (RELU) v = fmaxf(v, 0.0f);
      const int od = od0 + j * 4;
      if (OUTP)
        out[(size_t)(b * COUT + oc0 + c) * VOUT
            + ((size_t)(od + 1) * SOUT + (oh + 1)) * SOUT + (ow + 1)] = v;
      else
        out[(size_t)(b * COUT + oc0 + c) * VOUT
            + ((size_t)od * DOUT + oh) * DOUT + ow] = v;
    }
  }
}

// ---------------- transposed conv (k=4,s=2,p=1), TZ octets per thread -------
// r10/r13-proven body (xn block pinned via sched_barrier(0), tap-major/
// j-minor FMA order, two x4 uniform global weight tuples per (p,c)).
// r18: XCD-aware block swizzle. EPI: 0 none, 1 relu, 2 sigm.
template<int CIN, int COUT, int DIN, int OCG, int TZ, int EPI, int SIN,
         bool OUTP, int SOUT, int NG>
__global__ __launch_bounds__(256) WAVES_HINT
void k_convt(const float* __restrict__ xin, const float* __restrict__ wp,
             const float* __restrict__ bias, float* __restrict__ out) {
  constexpr int DOUT = 2 * DIN, NBX = DIN / 8, NBY = DIN / 8,
                NBZ = DIN / (4 * TZ);
  constexpr int NWG = 4 * NG * NBX * NBY * NBZ;
  static_assert(NWG % 8 == 0, "bijective XCD swizzle needs NWG%8==0");
  constexpr size_t VIN  = (size_t)SIN * SIN * SIN;
  constexpr size_t VOUT = OUTP ? (size_t)SOUT * SOUT * SOUT
                               : (size_t)DOUT * DOUT * DOUT;
  const int tid = threadIdx.x;
  const int tx = tid & 7, ty = (tid >> 3) & 7, tz = tid >> 6;
  const int bid = blockIdx.x;
  int bb = (bid & 7) * (NWG / 8) + (bid >> 3);
  const int g  = bb % NG;  bb /= NG;
  const int gx = bb % NBX; bb /= NBX;
  const int gy = bb % NBY; bb /= NBY;
  const int gz = bb % NBZ; bb /= NBZ;
  const int b = bb;
  const int oc0 = g * OCG;
  const int mx = gx * 8 + tx, my = gy * 8 + ty;
  const int mz0 = gz * (4 * TZ) + tz * TZ;

  float acc[TZ][8][OCG];
#pragma unroll
  for (int j = 0; j < TZ; ++j)
#pragma unroll
    for (int p = 0; p < 8; ++p)
#pragma unroll
      for (int c = 0; c < OCG; ++c) acc[j][p][c] = 0.0f;

#pragma unroll 1
  for (int ci = 0; ci < CIN; ++ci) {
    const float* xb = xin + (size_t)(b * CIN + ci) * VIN
                          + ((size_t)mz0 * SIN + my) * SIN + mx;
    float xn[TZ + 2][3][3];
#pragma unroll
    for (int dz = 0; dz < TZ + 2; ++dz)
#pragma unroll
      for (int dy = 0; dy < 3; ++dy) {
        const F3 t = ld3(xb + ((size_t)dz * SIN + dy) * SIN);
        xn[dz][dy][0] = t.x; xn[dz][dy][1] = t.y; xn[dz][dy][2] = t.z;
      }
    // Pin: all xn loads issue before any FMA below (overlap their latency
    // once, instead of the scheduler sinking each load next to its uses).
    __builtin_amdgcn_sched_barrier(0);

    const float* wci = wp + (size_t)ci * 8 * COUT * 16;
#pragma unroll
    for (int p = 0; p < 8; ++p) {
      const int pz = p >> 2, py = (p >> 1) & 1, px = p & 1;
#pragma unroll
      for (int c = 0; c < OCG; ++c) {
        const float* wb = wci + ((size_t)p * COUT + (oc0 + c)) * 16;
        const float4 wA = ld4(wb);      // az=0 taps (j = ay*2+ax)
        const float4 wB = ld4(wb + 8);  // az=1 taps
        // tap-major, j-minor: TZ independent FMAs between acc reuses
#pragma unroll
        for (int j = 0; j < TZ; ++j)
          acc[j][p][c] = fmaf(xn[j + pz][py    ][px    ], wA.x, acc[j][p][c]);
#pragma unroll
        for (int j = 0; j < TZ; ++j)
          acc[j][p][c] = fmaf(xn[j + pz][py    ][px + 1], wA.y, acc[j][p][c]);
#pragma unroll
        for (int j = 0; j < TZ; ++j)
          acc[j][p][c] = fmaf(xn[j + pz][py + 1][px    ], wA.z, acc[j][p][c]);
#pragma unroll
        for (int j = 0; j < TZ; ++j)
          acc[j][p][c] = fmaf(xn[j + pz][py + 1][px + 1], wA.w, acc[j][p][c]);
#pragma unroll
        for (int j = 0; j < TZ; ++j)
          acc[j][p][c] = fmaf(xn[j + pz + 1][py    ][px    ], wB.x, acc[j][p][c]);
#pragma unroll
        for (int j = 0; j < TZ; ++j)
          acc[j][p][c] = fmaf(xn[j + pz + 1][py    ][px + 1], wB.y, acc[j][p][c]);
#pragma unroll
        for (int j = 0; j < TZ; ++j)
          acc[j][p][c] = fmaf(xn[j + pz + 1][py + 1][px    ], wB.z, acc[j][p][c]);
#pragma unroll
        for (int j = 0; j < TZ; ++j)
          acc[j][p][c] = fmaf(xn[j + pz + 1][py + 1][px + 1], wB.w, acc[j][p][c]);
      }
    }
  }

#pragma unroll
  for (int c = 0; c < OCG; ++c) {
    const float bv = bias[oc0 + c];
#pragma unroll
    for (int j = 0; j < TZ; ++j) {
      const int mz = mz0 + j;
#pragma unroll
      for (int p = 0; p < 8; ++p) {
        const int pz = p >> 2, py = (p >> 1) & 1, px = p & 1;
        float v = acc[j][p][c] + bv;
        if (EPI == 1) v = fmaxf(v, 0.0f);
        if (EPI == 2) v = 1.0f / (1.0f + expf(-v));
        if (OUTP)
          out[(size_t)(b * COUT + oc0 + c) * VOUT
              + ((size_t)(2 * mz + pz + 1) * SOUT + (2 * my + py + 1)) * SOUT
              + (2 * mx + px + 1)] = v;
        else
          out[(size_t)(b * COUT + oc0 + c) * VOUT
              + ((size_t)(2 * mz + pz) * DOUT + (2 * my + py)) * DOUT
              + (2 * mx + px)] = v;
      }
    }
  }
}

// ---------------- VQ: argmin over 512 codes, gather codebook ----------------
__global__ __launch_bounds__(256) void k_vq(const float* __restrict__ ze,
                                            const float* __restrict__ cb,
                                            float* __restrict__ quant,
                                            float* __restrict__ quantp) {
  __shared__ float ct[64 * 65];
  __shared__ float zs[4][64];
  __shared__ int   bis[4];
  const int tid  = threadIdx.x;
  const int lane = tid & 63;
  const int wv   = tid >> 6;
  const int p0 = blockIdx.x * 4;
  const int b  = p0 >> 12;
  const int n0 = p0 & 4095;

  {
    const int c = tid >> 2, j = tid & 3;
    zs[j][c] = ze[((size_t)(b * 64 + c) << 12) + n0 + j];
  }

  float best = 3.4e38f;
  int bi = 0;
#pragma unroll 1
  for (int ch = 0; ch < 8; ++ch) {
    __syncthreads();
    for (int i = tid; i < 4096; i += 256) {
      const int r = i >> 6, c = i & 63;
      ct[r * 65 + c] = cb[((ch * 64 + r) << 6) + c];
    }
    __syncthreads();
    float d = 0.0f;
#pragma unroll 8
    for (int c = 0; c < 64; ++c) {
      const float t = zs[wv][c] - ct[lane * 65 + c];
      d = fmaf(t, t, d);
    }
    const int k = ch * 64 + lane;
    if (d < best) { best = d; bi = k; }
  }
#pragma unroll
  for (int off = 32; off > 0; off >>= 1) {
    const float ob = __shfl_down(best, off);
    const int   oi = __shfl_down(bi, off);
    if (ob < best || (ob == best && oi < bi)) { best = ob; bi = oi; }
  }
  if (lane == 0) bis[wv] = bi;
  __syncthreads();
  {
    const int c = tid >> 2, j = tid & 3;
    const float val = cb[(bis[j] << 6) + c];
    const int n = n0 + j;
    quant[((size_t)(b * 64 + c) << 12) + n] = val;
    const int zz = n >> 8, yy = (n >> 4) & 15, xx = n & 15;
    quantp[(size_t)(b * 64 + c) * 8000
           + ((size_t)(zz + 1) * 20 + (yy + 1)) * 20 + (xx + 1)] = val;
  }
}

// ---------------------------------------------------------------------------
extern "C" void kernel_launch(void* const* d_in, const int* in_sizes, int n_in,
                              void* d_out, int out_size, void* d_ws, size_t ws_size,
                              hipStream_t stream) {
  const float* x   = (const float*)d_in[0];
  const float* w1  = (const float*)d_in[1];
  const float* b1  = (const float*)d_in[2];
  const float* w2  = (const float*)d_in[3];
  const float* b2  = (const float*)d_in[4];
  const float* w3  = (const float*)d_in[5];
  const float* b3  = (const float*)d_in[6];
  const float* cb  = (const float*)d_in[7];
  const float* dw1 = (const float*)d_in[8];
  const float* db1 = (const float*)d_in[9];
  const float* dw2 = (const float*)d_in[10];
  const float* db2 = (const float*)d_in[11];
  const float* dw3 = (const float*)d_in[12];
  const float* db3 = (const float*)d_in[13];

  float* outf  = (float*)d_out;
  float* xhat  = outf;               // [4,1,128^3]
  float* quant = outf + 8388608;     // [4,64,16^3]
  float* ze    = outf + 9437184;     // [4,64,16^3]

  // d_out as scratch for padded input (4 x 130^3 = 8,788,000 floats).
  // Free until conv3 writes ze (offset 9,437,184 > 8,788,000), vq writes
  // quant, convt3 writes xhat — all strictly after conv1 consumes dp.
  float* dp = outf;

  // workspace layout
  float* regA = (float*)d_ws;                        // 64 x 68^3 (y1, d2)
  float* regB = regA + (size_t)64 * 68 * 68 * 68;    // 128 x 36^3 (y2, d1)
  float* regC = regB + (size_t)128 * 36 * 36 * 36;   // 256 x 20^3 (quantp)
  float* t1p = regC + (size_t)256 * 20 * 20 * 20;    // 64*8*32*16 = 262144
  float* t2p = t1p + 262144;                         // 32*8*16*16 = 65536
  float* t3p = t2p + 65536;                          // 16*8*1*16  = 2048

  // convT weight repacks + halo zeroing (ws re-poisoned every launch)
  k_repackT<64, 32><<<512, 256, 0, stream>>>(dw1, t1p);
  k_repackT<32, 16><<<128, 256, 0, stream>>>(dw2, t2p);
  k_repackT<16, 1><<<4, 256, 0, stream>>>(dw3, t3p);
  k_zhalo<68, 64, 64><<<78608, 256, 0, stream>>>(regA);
  k_zhalo<36, 32, 128><<<23328, 256, 0, stream>>>(regB);
  k_zhalo<20, 16, 256><<<8000, 256, 0, stream>>>(regC);
  // pad raw input into d_out scratch: x [4][128^3] -> dp [4][130^3]
  k_pad<<<34329, 256, 0, stream>>>(x, dp);

  // encoder
  // conv1: 1->16, out 64^3 — maskless padded-input path (SIN=130)
  k_conv<1, 16, 128, 64, 16, 2, true, true, 130, true, 68, 1>
      <<<2048, 256, 0, stream>>>(dp, w1, b1, regA);
  // conv2: 16->32, out 32^3 — high-residency clone: OCG 8, NG 4, grid 2048
  k_conv_hi<16, 32, 64, 32, 8, 1, true, true, 68, true, 36, 4>
      <<<2048, 256, 0, stream>>>(regA, w2, b2, regB);
  // conv3: 32->64, out 16^3
  k_conv<32, 64, 32, 16, 4, 1, false, true, 36, false, 16, 16>
      <<<1024, 256, 0, stream>>>(regB, w3, b3, ze);
  // vector quantization
  k_vq<<<4096, 256, 0, stream>>>(ze, cb, quant, regC);
  // decoder
  // convt1: 64->32, out 32^3 (TZ=1: grid 4b x NBZ4 x 2 x 2 x NG16 = 1024)
  k_convt<64, 32, 16, 2, 1, 1, 20, true, 36, 16>
      <<<1024, 256, 0, stream>>>(regC, t1p, db1, regB);
  // convt2: 32->16, out 64^3 (TZ=2: grid 4b x NBZ4 x 4 x 4 x NG8 = 2048)
  k_convt<32, 16, 32, 2, 2, 1, 36, true, 68, 8>
      <<<2048, 256, 0, stream>>>(regB, t2p, db2, regA);
  // convt3: 16->1, out 128^3 (TZ=4: grid 4b x NBZ4 x 8 x 8 x NG1 = 1024)
  k_convt<16, 1, 64, 1, 4, 2, 68, false, 0, 1>
      <<<1024, 256, 0, stream>>>(regA, t3p, db3, xhat);
}

// Round 15
// 968.311 us; speedup vs baseline: 1.0177x; 1.0177x over previous
//
#include <hip/hip_runtime.h>
#include <math.h>

// ---------------------------------------------------------------------------
// VQ-VAE 3D forward, round 22 (= r21 resubmitted; r21 bench was an infra
// failure "container failed twice" — no counters, no verdict. Source
// re-audited: LDS bounds conv1 129<=129 / conv2 65<=67 / conv3 33<=35,
// LDS 25.9/28.8KB, memcpy-based unaligned LDS reads, NWG%8==0. No fault
// vector; resubmitting unchanged to get the TA-pipe measurement.)
//
// r20 post-mortem: occupancy 35->61% (VGPR 12!) with dur 193->201 and VALU
// flat 38% -> TLP null. With ILP (r9-r17), traffic (r18), TLP (r20) all
// excluded, the saturated invisible resource is the TA (vector-mem address)
// pipe: conv's stride-2 input ld4 touches ~16 cache lines per wave-instr
// (~16 TA-cy vs 1-2 coalesced). 16 ld4/ci x 16 lines x 16 waves/CU x 16 ci
// ~ 110us/CU -- matches the stubborn ~193. Also explains r9's convt null
// (ld3 is stride-1 = already few-line) and weight-LDS nulls (SGPR=112:
// weights already scalar-pipe).
// r21/r22: k_conv inputs staged in LDS via COALESCED float2 cooperative
// loads (r9's proven dbuf skeleton): conv2/3 [2][10][18][20] (28.8KB),
// conv1 stage-once [18][18][20] (25.9KB). Staging = 7 coalesced wave-loads
// per ci (~8 lines each) -> ~4-5x TA reduction; per-thread reads move to
// LDS. conv2 at r19 geometry (OCG16/NG2/1024).
// convt/vq/swizzle byte-identical to r19.
// ---------------------------------------------------------------------------

__device__ __forceinline__ float4 ld4(const float* p) {
  float4 q; __builtin_memcpy(&q, p, 16); return q;
}
struct F2 { float x, y; };
__device__ __forceinline__ F2 ld2(const float* p) {
  F2 q; __builtin_memcpy(&q, p, 8); return q;
}
struct F3 { float x, y, z; };
__device__ __forceinline__ F3 ld3(const float* p) {
  F3 q; __builtin_memcpy(&q, p, 12); return q;
}
__device__ __forceinline__ float4 ldl4(const float* p) {  // LDS float4
  float4 q; __builtin_memcpy(&q, p, 16); return q;
}

#define WAVES_HINT __attribute__((amdgpu_waves_per_eu(2, 4)))

// ---------------- convT weight repack: -> Wp[ci][p][co][2][8] ---------------
template<int CIN, int COUT>
__global__ __launch_bounds__(256) void k_repackT(const float* __restrict__ w,
                                                 float* __restrict__ dst) {
  const int idx = blockIdx.x * 256 + threadIdx.x;
  if (idx >= CIN * 8 * COUT * 8) return;
  const int a  = idx & 7;
  const int co = (idx >> 3) % COUT;
  const int p  = ((idx >> 3) / COUT) & 7;
  const int ci2 = idx / (8 * COUT * 8);
  const int az = a >> 2, ay = (a >> 1) & 1, ax = a & 1;
  const int pz = p >> 2, py = (p >> 1) & 1, px = p & 1;
  const int kz = 3 - pz - 2 * az, ky = 3 - py - 2 * ay, kx = 3 - px - 2 * ax;
  dst[(((size_t)(ci2 * 8 + p) * COUT + co) * 16) + az * 8 + (ay * 2 + ax)] =
      w[((size_t)ci2 * COUT + co) * 64 + (kz * 16 + ky * 4 + kx)];
}

// ---------------- halo zeroing for padded buffers ---------------------------
template<int S, int D, int NCH>
__global__ __launch_bounds__(256) void k_zhalo(float* __restrict__ buf) {
  const int vol = S * S * S;
  const long long idx = (long long)blockIdx.x * 256 + threadIdx.x;
  if (idx >= (long long)NCH * vol) return;
  const int r = (int)(idx % vol);
  const int z = r / (S * S), y = (r / S) % S, x = r % S;
  if (z < 1 || z > D || y < 1 || y > D || x < 1 || x > D) buf[idx] = 0.0f;
}

// ---------------- pad raw input x [4][128^3] -> dp [4][130^3] ---------------
__global__ __launch_bounds__(256) void k_pad(const float* __restrict__ x,
                                             float* __restrict__ dp) {
  constexpr long long VOL = 130LL * 130 * 130;
  const long long idx = (long long)blockIdx.x * 256 + threadIdx.x;
  if (idx >= 4 * VOL) return;
  const int b = (int)(idx / VOL);
  const int r = (int)(idx % VOL);
  const int z = r / (130 * 130), y = (r / 130) % 130, xx = r % 130;
  float v = 0.0f;
  if (z >= 1 && z <= 128 && y >= 1 && y <= 128 && xx >= 1 && xx <= 128)
    v = x[(((long long)b * 128 + (z - 1)) * 128 + (y - 1)) * 128 + (xx - 1)];
  dp[idx] = v;
}

// ---------------- forward conv (k=4,s=2,p=1), LDS-staged input --------------
// INP=true (all uses): input tile [ZT][18][18] staged into LDS (x-pad to 20)
// via coalesced float2 cooperative loads; double-buffered across ci for
// CIN>1, stage-once for CIN==1. Per-thread xn reads come from LDS (no TA).
// Weights: one x4 uniform tuple per consume point (scalar-pipe, proven).
// r18 XCD swizzle retained.
template<int CIN, int COUT, int DIN, int DOUT, int OCG, int TZ, bool RELU,
         bool INP, int SIN, bool OUTP, int SOUT, int NG>
__global__ __launch_bounds__(256) WAVES_HINT
void k_conv(const float* __restrict__ xin, const float* __restrict__ wg,
            const float* __restrict__ bias, float* __restrict__ out) {
  constexpr int NBX = DOUT / 8, NBY = DOUT / 8, NBZ = DOUT / (4 * TZ);
  constexpr int NWG = 4 * NG * NBX * NBY * NBZ;
  static_assert(NWG % 8 == 0, "bijective XCD swizzle needs NWG%8==0");
  constexpr size_t VIN  = (size_t)SIN * SIN * SIN;
  constexpr size_t VOUT = OUTP ? (size_t)SOUT * SOUT * SOUT : (size_t)DOUT * DOUT * DOUT;
  // LDS tile geometry
  constexpr int XT = 18, YT = 18, ZT = 8 * TZ + 2, XTP = 20;
  constexpr int NF2 = ZT * YT * (XT / 2);        // float2 elements per tile
  constexpr int NR  = (NF2 + 255) / 256;         // cooperative rounds
  constexpr int NBUF = (CIN > 1) ? 2 : 1;
  constexpr int TVOL = ZT * YT * XTP;
  __shared__ float lds[NBUF][ZT][YT][XTP];

  const int tid = threadIdx.x;
  const int tx = tid & 7, ty = (tid >> 3) & 7, tz = tid >> 6;
  const int bid = blockIdx.x;
  int bb = (bid & 7) * (NWG / 8) + (bid >> 3);
  const int g  = bb % NG;  bb /= NG;
  const int gx = bb % NBX; bb /= NBX;
  const int gy = bb % NBY; bb /= NBY;
  const int gz = bb % NBZ; bb /= NBZ;
  const int b = bb;
  const int oc0 = g * OCG;
  const int ow = gx * 8 + tx, oh = gy * 8 + ty, od0 = gz * (4 * TZ) + tz;

  // tile origin in padded input coords
  const int x0 = gx * 16, y0 = gy * 16, z0 = gz * (8 * TZ);
  const float* xt0 = xin + (size_t)b * CIN * VIN
                   + ((size_t)z0 * SIN + y0) * SIN + x0;
  float* ldsf = &lds[0][0][0][0];

  float acc[TZ][OCG];
#pragma unroll
  for (int j = 0; j < TZ; ++j)
#pragma unroll
    for (int c = 0; c < OCG; ++c) acc[j][c] = 0.0f;

  if constexpr (CIN == 1) {
    // ---- stage once, coalesced float2 ----
    for (int e = tid; e < NF2; e += 256) {
      const int ez = e / (YT * (XT / 2));
      const int rem = e - ez * (YT * (XT / 2));
      const int ey = rem / (XT / 2);
      const int m  = rem - ey * (XT / 2);
      const F2 v = ld2(xt0 + ((size_t)ez * SIN + ey) * SIN + 2 * m);
      *(F2*)&lds[0][ez][ey][2 * m] = v;
    }
    __syncthreads();

#pragma unroll 1
    for (int t16 = 0; t16 < 16; ++t16) {
      const int dy = t16 & 3, dz = t16 >> 2;
      float4 q[TZ];
#pragma unroll
      for (int j = 0; j < TZ; ++j) {
        const int zp = (tz + 4 * j) * 2 + dz;
        q[j] = ldl4(&lds[0][zp][2 * ty + dy][2 * tx]);
      }
#pragma unroll
      for (int c = 0; c < OCG; ++c) {
        const float4 w4 = ld4(wg + (size_t)(oc0 + c) * 64 + t16 * 4);
#pragma unroll
        for (int j = 0; j < TZ; ++j) {
          acc[j][c] = fmaf(q[j].x, w4.x, acc[j][c]);
          acc[j][c] = fmaf(q[j].y, w4.y, acc[j][c]);
          acc[j][c] = fmaf(q[j].z, w4.z, acc[j][c]);
          acc[j][c] = fmaf(q[j].w, w4.w, acc[j][c]);
        }
      }
    }
  } else {
    // ---- double-buffered per-ci staging (r9-proven skeleton) ----
    int goff[NR], loff[NR];
#pragma unroll
    for (int r = 0; r < NR; ++r) {
      const int e = tid + 256 * r;
      const int ez = e / (YT * (XT / 2));
      const int rem = e - ez * (YT * (XT / 2));
      const int ey = rem / (XT / 2);
      const int m  = rem - ey * (XT / 2);
      goff[r] = (ez * SIN + ey) * SIN + 2 * m;
      loff[r] = (ez * YT + ey) * XTP + 2 * m;
    }

    // prologue: stage ci=0 into buffer 0
#pragma unroll
    for (int r = 0; r < NR; ++r)
      if (tid + 256 * r < NF2) {
        const F2 v = ld2(xt0 + goff[r]);
        *(F2*)&ldsf[loff[r]] = v;
      }
    __syncthreads();

#pragma unroll 1
    for (int ci = 0; ci < CIN; ++ci) {
      // prefetch next ci's tile into registers (hides under FMA body)
      F2 rg[NR];
      const bool pf = (ci + 1 < CIN);
      if (pf) {
        const float* xc = xt0 + (size_t)(ci + 1) * VIN;
#pragma unroll
        for (int r = 0; r < NR; ++r)
          if (tid + 256 * r < NF2) rg[r] = ld2(xc + goff[r]);
      }
      const int cur = ci & 1;
      const float* Lb = ldsf + cur * TVOL;

#pragma unroll 1
      for (int t16 = 0; t16 < 16; ++t16) {
        const int dy = t16 & 3, dz = t16 >> 2;
        float4 q[TZ];
#pragma unroll
        for (int j = 0; j < TZ; ++j) {
          const int zp = (tz + 4 * j) * 2 + dz;
          q[j] = ldl4(Lb + ((size_t)zp * YT + (2 * ty + dy)) * XTP + 2 * tx);
        }
#pragma unroll
        for (int c = 0; c < OCG; ++c) {
          const float4 w4 =
              ld4(wg + ((size_t)(oc0 + c) * CIN + ci) * 64 + t16 * 4);
#pragma unroll
          for (int j = 0; j < TZ; ++j) {
            acc[j][c] = fmaf(q[j].x, w4.x, acc[j][c]);
            acc[j][c] = fmaf(q[j].y, w4.y, acc[j][c]);
            acc[j][c] = fmaf(q[j].z, w4.z, acc[j][c]);
            acc[j][c] = fmaf(q[j].w, w4.w, acc[j][c]);
          }
        }
      }

      // dbuf handoff (r9-proven ordering)
      __syncthreads();
      if (pf) {
        float* Ln = ldsf + (cur ^ 1) * TVOL;
#pragma unroll
        for (int r = 0; r < NR; ++r)
          if (tid + 256 * r < NF2) *(F2*)&Ln[loff[r]] = rg[r];
      }
      __syncthreads();
    }
  }

#pragma unroll
  for (int c = 0; c < OCG; ++c) {
    const float bv = bias[oc0 + c];
#pragma unroll
    for (int j = 0; j < TZ; ++j) {
      float v = acc[j][c] + bv;
      if (RELU) v = fmaxf(v, 0.0f);
      const int od = od0 + j * 4;
      if (OUTP)
        out[(size_t)(b * COUT + oc0 + c) * VOUT
            + ((size_t)(od + 1) * SOUT + (oh + 1)) * SOUT + (ow + 1)] = v;
      else
        out[(size_t)(b * COUT + oc0 + c) * VOUT
            + ((size_t)od * DOUT + oh) * DOUT + ow] = v;
    }
  }
}

// ---------------- transposed conv (k=4,s=2,p=1), TZ octets per thread -------
// r10/r13-proven body + r18 swizzle. EPI: 0 none, 1 relu, 2 sigm.
template<int CIN, int COUT, int DIN, int OCG, int TZ, int EPI, int SIN,
         bool OUTP, int SOUT, int NG>
__global__ __launch_bounds__(256) WAVES_HINT
void k_convt(const float* __restrict__ xin, const float* __restrict__ wp,
             const float* __restrict__ bias, float* __restrict__ out) {
  constexpr int DOUT = 2 * DIN, NBX = DIN / 8, NBY = DIN / 8,
                NBZ = DIN / (4 * TZ);
  constexpr int NWG = 4 * NG * NBX * NBY * NBZ;
  static_assert(NWG % 8 == 0, "bijective XCD swizzle needs NWG%8==0");
  constexpr size_t VIN  = (size_t)SIN * SIN * SIN;
  constexpr size_t VOUT = OUTP ? (size_t)SOUT * SOUT * SOUT
                               : (size_t)DOUT * DOUT * DOUT;
  const int tid = threadIdx.x;
  const int tx = tid & 7, ty = (tid >> 3) & 7, tz = tid >> 6;
  const int bid = blockIdx.x;
  int bb = (bid & 7) * (NWG / 8) + (bid >> 3);
  const int g  = bb % NG;  bb /= NG;
  const int gx = bb % NBX; bb /= NBX;
  const int gy = bb % NBY; bb /= NBY;
  const int gz = bb % NBZ; bb /= NBZ;
  const int b = bb;
  const int oc0 = g * OCG;
  const int mx = gx * 8 + tx, my = gy * 8 + ty;
  const int mz0 = gz * (4 * TZ) + tz * TZ;

  float acc[TZ][8][OCG];
#pragma unroll
  for (int j = 0; j < TZ; ++j)
#pragma unroll
    for (int p = 0; p < 8; ++p)
#pragma unroll
      for (int c = 0; c < OCG; ++c) acc[j][p][c] = 0.0f;

#pragma unroll 1
  for (int ci = 0; ci < CIN; ++ci) {
    const float* xb = xin + (size_t)(b * CIN + ci) * VIN
                          + ((size_t)mz0 * SIN + my) * SIN + mx;
    float xn[TZ + 2][3][3];
#pragma unroll
    for (int dz = 0; dz < TZ + 2; ++dz)
#pragma unroll
      for (int dy = 0; dy < 3; ++dy) {
        const F3 t = ld3(xb + ((size_t)dz * SIN + dy) * SIN);
        xn[dz][dy][0] = t.x; xn[dz][dy][1] = t.y; xn[dz][dy][2] = t.z;
      }
    __builtin_amdgcn_sched_barrier(0);

    const float* wci = wp + (size_t)ci * 8 * COUT * 16;
#pragma unroll
    for (int p = 0; p < 8; ++p) {
      const int pz = p >> 2, py = (p >> 1) & 1, px = p & 1;
#pragma unroll
      for (int c = 0; c < OCG; ++c) {
        const float* wb = wci + ((size_t)p * COUT + (oc0 + c)) * 16;
        const float4 wA = ld4(wb);      // az=0 taps (j = ay*2+ax)
        const float4 wB = ld4(wb + 8);  // az=1 taps
#pragma unroll
        for (int j = 0; j < TZ; ++j)
          acc[j][p][c] = fmaf(xn[j + pz][py    ][px    ], wA.x, acc[j][p][c]);
#pragma unroll
        for (int j = 0; j < TZ; ++j)
          acc[j][p][c] = fmaf(xn[j + pz][py    ][px + 1], wA.y, acc[j][p][c]);
#pragma unroll
        for (int j = 0; j < TZ; ++j)
          acc[j][p][c] = fmaf(xn[j + pz][py + 1][px    ], wA.z, acc[j][p][c]);
#pragma unroll
        for (int j = 0; j < TZ; ++j)
          acc[j][p][c] = fmaf(xn[j + pz][py + 1][px + 1], wA.w, acc[j][p][c]);
#pragma unroll
        for (int j = 0; j < TZ; ++j)
          acc[j][p][c] = fmaf(xn[j + pz + 1][py    ][px    ], wB.x, acc[j][p][c]);
#pragma unroll
        for (int j = 0; j < TZ; ++j)
          acc[j][p][c] = fmaf(xn[j + pz + 1][py    ][px + 1], wB.y, acc[j][p][c]);
#pragma unroll
        for (int j = 0; j < TZ; ++j)
          acc[j][p][c] = fmaf(xn[j + pz + 1][py + 1][px    ], wB.z, acc[j][p][c]);
#pragma unroll
        for (int j = 0; j < TZ; ++j)
          acc[j][p][c] = fmaf(xn[j + pz + 1][py + 1][px + 1], wB.w, acc[j][p][c]);
      }
    }
  }

#pragma unroll
  for (int c = 0; c < OCG; ++c) {
    const float bv = bias[oc0 + c];
#pragma unroll
    for (int j = 0; j < TZ; ++j) {
      const int mz = mz0 + j;
#pragma unroll
      for (int p = 0; p < 8; ++p) {
        const int pz = p >> 2, py = (p >> 1) & 1, px = p & 1;
        float v = acc[j][p][c] + bv;
        if (EPI == 1) v = fmaxf(v, 0.0f);
        if (EPI == 2) v = 1.0f / (1.0f + expf(-v));
        if (OUTP)
          out[(size_t)(b * COUT + oc0 + c) * VOUT
              + ((size_t)(2 * mz + pz + 1) * SOUT + (2 * my + py + 1)) * SOUT
              + (2 * mx + px + 1)] = v;
        else
          out[(size_t)(b * COUT + oc0 + c) * VOUT
              + ((size_t)(2 * mz + pz) * DOUT + (2 * my + py)) * DOUT
              + (2 * mx + px)] = v;
      }
    }
  }
}

// ---------------- VQ: argmin over 512 codes, gather codebook ----------------
__global__ __launch_bounds__(256) void k_vq(const float* __restrict__ ze,
                                            const float* __restrict__ cb,
                                            float* __restrict__ quant,
                                            float* __restrict__ quantp) {
  __shared__ float ct[64 * 65];
  __shared__ float zs[4][64];
  __shared__ int   bis[4];
  const int tid  = threadIdx.x;
  const int lane = tid & 63;
  const int wv   = tid >> 6;
  const int p0 = blockIdx.x * 4;
  const int b  = p0 >> 12;
  const int n0 = p0 & 4095;

  {
    const int c = tid >> 2, j = tid & 3;
    zs[j][c] = ze[((size_t)(b * 64 + c) << 12) + n0 + j];
  }

  float best = 3.4e38f;
  int bi = 0;
#pragma unroll 1
  for (int ch = 0; ch < 8; ++ch) {
    __syncthreads();
    for (int i = tid; i < 4096; i += 256) {
      const int r = i >> 6, c = i & 63;
      ct[r * 65 + c] = cb[((ch * 64 + r) << 6) + c];
    }
    __syncthreads();
    float d = 0.0f;
#pragma unroll 8
    for (int c = 0; c < 64; ++c) {
      const float t = zs[wv][c] - ct[lane * 65 + c];
      d = fmaf(t, t, d);
    }
    const int k = ch * 64 + lane;
    if (d < best) { best = d; bi = k; }
  }
#pragma unroll
  for (int off = 32; off > 0; off >>= 1) {
    const float ob = __shfl_down(best, off);
    const int   oi = __shfl_down(bi, off);
    if (ob < best || (ob == best && oi < bi)) { best = ob; bi = oi; }
  }
  if (lane == 0) bis[wv] = bi;
  __syncthreads();
  {
    const int c = tid >> 2, j = tid & 3;
    const float val = cb[(bis[j] << 6) + c];
    const int n = n0 + j;
    quant[((size_t)(b * 64 + c) << 12) + n] = val;
    const int zz = n >> 8, yy = (n >> 4) & 15, xx = n & 15;
    quantp[(size_t)(b * 64 + c) * 8000
           + ((size_t)(zz + 1) * 20 + (yy + 1)) * 20 + (xx + 1)] = val;
  }
}

// ---------------------------------------------------------------------------
extern "C" void kernel_launch(void* const* d_in, const int* in_sizes, int n_in,
                              void* d_out, int out_size, void* d_ws, size_t ws_size,
                              hipStream_t stream) {
  const float* x   = (const float*)d_in[0];
  const float* w1  = (const float*)d_in[1];
  const float* b1  = (const float*)d_in[2];
  const float* w2  = (const float*)d_in[3];
  const float* b2  = (const float*)d_in[4];
  const float* w3  = (const float*)d_in[5];
  const float* b3  = (const float*)d_in[6];
  const float* cb  = (const float*)d_in[7];
  const float* dw1 = (const float*)d_in[8];
  const float* db1 = (const float*)d_in[9];
  const float* dw2 = (const float*)d_in[10];
  const float* db2 = (const float*)d_in[11];
  const float* dw3 = (const float*)d_in[12];
  const float* db3 = (const float*)d_in[13];

  float* outf  = (float*)d_out;
  float* xhat  = outf;               // [4,1,128^3]
  float* quant = outf + 8388608;     // [4,64,16^3]
  float* ze    = outf + 9437184;     // [4,64,16^3]

  // d_out as scratch for padded input (4 x 130^3 = 8,788,000 floats).
  // Free until conv3 writes ze (offset 9,437,184 > 8,788,000), vq writes
  // quant, convt3 writes xhat — all strictly after conv1 consumes dp.
  float* dp = outf;

  // workspace layout
  float* regA = (float*)d_ws;                        // 64 x 68^3 (y1, d2)
  float* regB = regA + (size_t)64 * 68 * 68 * 68;    // 128 x 36^3 (y2, d1)
  float* regC = regB + (size_t)128 * 36 * 36 * 36;   // 256 x 20^3 (quantp)
  float* t1p = regC + (size_t)256 * 20 * 20 * 20;    // 64*8*32*16 = 262144
  float* t2p = t1p + 262144;                         // 32*8*16*16 = 65536
  float* t3p = t2p + 65536;                          // 16*8*1*16  = 2048

  // convT weight repacks + halo zeroing (ws re-poisoned every launch)
  k_repackT<64, 32><<<512, 256, 0, stream>>>(dw1, t1p);
  k_repackT<32, 16><<<128, 256, 0, stream>>>(dw2, t2p);
  k_repackT<16, 1><<<4, 256, 0, stream>>>(dw3, t3p);
  k_zhalo<68, 64, 64><<<78608, 256, 0, stream>>>(regA);
  k_zhalo<36, 32, 128><<<23328, 256, 0, stream>>>(regB);
  k_zhalo<20, 16, 256><<<8000, 256, 0, stream>>>(regC);
  // pad raw input into d_out scratch: x [4][128^3] -> dp [4][130^3]
  k_pad<<<34329, 256, 0, stream>>>(x, dp);

  // encoder
  // conv1: 1->16, out 64^3 — LDS-staged input (stage-once), SIN=130
  k_conv<1, 16, 128, 64, 16, 2, true, true, 130, true, 68, 1>
      <<<2048, 256, 0, stream>>>(dp, w1, b1, regA);
  // conv2: 16->32, out 32^3 — LDS-staged dbuf (r19 geometry)
  k_conv<16, 32, 64, 32, 16, 1, true, true, 68, true, 36, 2>
      <<<1024, 256, 0, stream>>>(regA, w2, b2, regB);
  // conv3: 32->64, out 16^3 — LDS-staged dbuf
  k_conv<32, 64, 32, 16, 4, 1, false, true, 36, false, 16, 16>
      <<<1024, 256, 0, stream>>>(regB, w3, b3, ze);
  // vector quantization
  k_vq<<<4096, 256, 0, stream>>>(ze, cb, quant, regC);
  // decoder
  // convt1: 64->32, out 32^3 (TZ=1: grid 1024)
  k_convt<64, 32, 16, 2, 1, 1, 20, true, 36, 16>
      <<<1024, 256, 0, stream>>>(regC, t1p, db1, regB);
  // convt2: 32->16, out 64^3 (TZ=2: grid 2048)
  k_convt<32, 16, 32, 2, 2, 1, 36, true, 68, 8>
      <<<2048, 256, 0, stream>>>(regB, t2p, db2, regA);
  // convt3: 16->1, out 128^3 (TZ=4: grid 1024)
  k_convt<16, 1, 64, 1, 4, 2, 68, false, 0, 1>
      <<<1024, 256, 0, stream>>>(regA, t3p, db3, xhat);
}